// Round 6
// baseline (310.788 us; speedup 1.0000x reference)
//
#include <hip/hip_runtime.h>
#include <hip/hip_bf16.h>
#include <stdint.h>

// SpatialMHA: B=64 S=256 E=1024 H=16 D=64
// qkv = x @ Win^T + bin ; attn with additive spatial bias ; out = x + ctx @ Wout^T + bout

typedef __attribute__((ext_vector_type(8))) __bf16 bf16x8;
typedef __attribute__((ext_vector_type(4))) float f32x4;

#define DEVI static __device__ __forceinline__

DEVI unsigned short f2bf(float f) {           // fp32 -> bf16 round-to-nearest-even
  union { float f; unsigned u; } x; x.f = f;
  unsigned r = x.u + 0x7fffu + ((x.u >> 16) & 1u);
  return (unsigned short)(r >> 16);
}

typedef unsigned int __attribute__((address_space(1))) u32_g;
typedef unsigned int __attribute__((address_space(3))) u32_l;

DEVI void g2l16(const unsigned short* g, unsigned short* l) {
  // async global->LDS, 16B per lane; LDS dest = wave-uniform base + lane*16
  __builtin_amdgcn_global_load_lds((const u32_g*)g, (u32_l*)l, 16, 0, 0);
}

// ---------------------------------------------------------------- fp32->bf16
__global__ __launch_bounds__(256) void cvt_kernel(const float* __restrict__ s,
                                                  unsigned short* __restrict__ d, int n) {
  int i = (blockIdx.x * 256 + threadIdx.x) * 4;
  if (i >= n) return;
  float4 v = *(const float4*)(s + i);
  ushort4 o;
  o.x = f2bf(v.x); o.y = f2bf(v.y); o.z = f2bf(v.z); o.w = f2bf(v.w);
  *(ushort4*)(d + i) = o;
}

// ---------------------------------------------------------------- 256x128 GEMM, 4 waves
// C[m,n] = sum_k A[m,k]*Bw[n,k]; K=1024 = 32 slabs of BK=32. 4 waves (2M x 2N),
// per-wave 128x64 C (acc = 128 AGPR). LDS: 3-slot ring x 24KB (A 256x32 + B 128x32)
// = 72KB -> 2 blocks/CU co-resident (TLP overlap: one block's MFMA covers the
// other's LDS/barrier stalls, m114). Per-wave regs: acc128 + a[8]+b[4] frags 48
// (single-phase lifetime) + addr ~30 = ~205 <= 256 cap -> no spill (the R2-R4
// 8-wave designs demanded ~264+ and spilled; FETCH/WRITE showed the scratch).
// Phase p: BARR; STAGE(p+2); LOADF(p); lgkm(0); sched_barrier; 32 MFMA; vmcnt(6).
//   safety: STAGE(p+2) (slot (p-1)%3) issued after BARR(p) => all waves drained
//     their slot-(p-1) reads (their lgkm@p-1 precedes BARR(p)).
//   availability: vmcnt(6)@p-1 leaves only STAGE(p+1) in flight => slab p landed
//     for every wave before it passes BARR(p); LOADF(p) after BARR(p) is safe.
// Swizzle: 16B granule ^= ((row>>1)&3) on stage source and ds_read (R1/R2: 0 conflicts).
template <int EPI>
__global__ __launch_bounds__(256, 2)
void gemm4(const unsigned short* __restrict__ A,
           const unsigned short* __restrict__ Bw,
           const float* __restrict__ bias,
           unsigned short* __restrict__ Qo,
           unsigned short* __restrict__ Ko,
           unsigned short* __restrict__ VTo,
           const float* __restrict__ Xres,
           float* __restrict__ Out) {
  extern __shared__ unsigned short lds[];   // 3 * 12288 elems (A 8192 + B 4096 each)
  const int lane = threadIdx.x & 63, wid = threadIdx.x >> 6;
  const int l15 = lane & 15, lg = lane >> 4;
  const int wr = wid >> 1, wcn = wid & 1;
  const int am0 = blockIdx.x * 256, bn0 = blockIdx.y * 128;

  const int srow0 = wid * 16 + (lane >> 2);   // 0..63 staging row (+ j*64)
  const int scb0  = (lane & 3) * 16;          // staging linear col-byte

  f32x4 acc[8][4] = {};
  bf16x8 a[8], b[4];

#define SWZ(row) ((((row) >> 1) & 3) << 4)
#define VMC(N) asm volatile("s_waitcnt vmcnt(" #N ")" ::: "memory")

#define STAGE(s) { \
    const int slot_ = (s) % 3; \
    _Pragma("unroll") \
    for (int j = 0; j < 4; ++j) { \
      const int row_ = j * 64 + srow0; \
      const int cs_ = scb0 ^ SWZ(row_); \
      g2l16(A + (size_t)(am0 + row_) * 1024 + (s) * 32 + (cs_ >> 1), \
            &lds[slot_ * 12288 + (j * 64 + wid * 16) * 32]); \
    } \
    _Pragma("unroll") \
    for (int j = 0; j < 2; ++j) { \
      const int row_ = j * 64 + srow0; \
      const int cs_ = scb0 ^ SWZ(row_); \
      g2l16(Bw + (size_t)(bn0 + row_) * 1024 + (s) * 32 + (cs_ >> 1), \
            &lds[slot_ * 12288 + 8192 + (j * 64 + wid * 16) * 32]); \
    } }

#define LOADF(p) { \
    const unsigned short* As_ = &lds[((p) % 3) * 12288]; \
    const unsigned short* Bs_ = As_ + 8192; \
    _Pragma("unroll") \
    for (int mf = 0; mf < 8; ++mf) { \
      const int row_ = wr * 128 + mf * 16 + l15; \
      a[mf] = *(const bf16x8*)((const char*)As_ + row_ * 64 + ((lg * 16) ^ SWZ(row_))); \
    } \
    _Pragma("unroll") \
    for (int nf = 0; nf < 4; ++nf) { \
      const int row_ = wcn * 64 + nf * 16 + l15; \
      b[nf] = *(const bf16x8*)((const char*)Bs_ + row_ * 64 + ((lg * 16) ^ SWZ(row_))); \
    } }

#define MM() { \
    __builtin_amdgcn_s_setprio(1); \
    _Pragma("unroll") \
    for (int mf = 0; mf < 8; ++mf) \
      _Pragma("unroll") \
      for (int nf = 0; nf < 4; ++nf) \
        acc[mf][nf] = __builtin_amdgcn_mfma_f32_16x16x32_bf16(a[mf], b[nf], acc[mf][nf], 0, 0, 0); \
    __builtin_amdgcn_s_setprio(0); }

  STAGE(0) STAGE(1)
  VMC(6);   // slab0 landed (this wave); slab1 in flight

#pragma unroll 1
  for (int p = 0; p < 32; ++p) {
    __builtin_amdgcn_s_barrier();
    if (p < 30) STAGE(p + 2)
    LOADF(p)
    asm volatile("s_waitcnt lgkmcnt(0)" ::: "memory");
    __builtin_amdgcn_sched_barrier(0);
    MM()
    if (p < 29) { VMC(6); } else { VMC(0); }
  }

  // C frag mapping: col = bn0 + wcn*64 + nf*16 + l15 ; row = am0 + wr*128 + mf*16 + lg*4 + r
  if (EPI == 0) {
#pragma unroll
    for (int nf = 0; nf < 4; ++nf) {
      const int col = bn0 + wcn * 64 + nf * 16 + l15;   // 0..3071
      const int which = col >> 10;                      // 0=Q 1=K 2=V (uniform per block)
      const int e = col & 1023;
      const int hh = e >> 6, dd = e & 63;
      const float bv = bias[col];
#pragma unroll
      for (int mf = 0; mf < 8; ++mf) {
        const int row0 = am0 + wr * 128 + mf * 16 + lg * 4;  // multiple of 4
        const int bb = row0 >> 8;
        const int s0 = row0 & 255;
        if (which == 2) {
          unsigned long long pk = 0;
#pragma unroll
          for (int r = 0; r < 4; ++r)
            pk |= (unsigned long long)f2bf(acc[mf][nf][r] + bv) << (16 * r);
          *(unsigned long long*)&VTo[((size_t)(bb * 16 + hh) * 64 + dd) * 256 + s0] = pk;
        } else {
          unsigned short* dst = (which == 0) ? Qo : Ko;
#pragma unroll
          for (int r = 0; r < 4; ++r)
            dst[((size_t)(bb * 16 + hh) * 256 + s0 + r) * 64 + dd] = f2bf(acc[mf][nf][r] + bv);
        }
      }
    }
  } else {
#pragma unroll
    for (int nf = 0; nf < 4; ++nf) {
      const int col = bn0 + wcn * 64 + nf * 16 + l15;
      const float bv = bias[col];
#pragma unroll
      for (int mf = 0; mf < 8; ++mf) {
#pragma unroll
        for (int r = 0; r < 4; ++r) {
          const int row = am0 + wr * 128 + mf * 16 + lg * 4 + r;
          const size_t idx = (size_t)row * 1024 + col;
          Out[idx] = Xres[idx] + acc[mf][nf][r] + bv;
        }
      }
    }
  }
#undef SWZ
#undef VMC
#undef STAGE
#undef LOADF
#undef MM
}

// ---------------------------------------------------------------- fused attention
// One block per (b,h); 4 waves x 64 q rows. FA2 online softmax over 8 key chunks
// of 32 (was 4x64: s[] halved 64->32 regs, peak ~220 -> no spill, 2 blocks/CU).
// Latency hiding: bias loads issued before QK^T (MFMA covers them); next chunk's
// K frags + this chunk's V frags issued before softmax (VALU covers them).
// P staged per-wave in padded LDS [64][40] via packed ds_write_b64.
__global__ __launch_bounds__(256, 2)
void attn_kernel(const unsigned short* __restrict__ Qg,
                 const unsigned short* __restrict__ Kg,
                 const unsigned short* __restrict__ VTg,
                 const float* __restrict__ bias,
                 unsigned short* __restrict__ ctx) {
  __shared__ unsigned short P[4][64][40];   // per-wave private [q][k32], pad 32->40 (20KB)
  const int lane = threadIdx.x & 63, wave = threadIdx.x >> 6;
  const int l15 = lane & 15, lg = lane >> 4;
  const int bh = blockIdx.x;
  const int bb = bh >> 4, hh = bh & 15;
  const size_t base = (size_t)bh * (256 * 64);
  const int q0 = wave * 64;

  bf16x8 qfr[4][2];
#pragma unroll
  for (int qi = 0; qi < 4; ++qi)
#pragma unroll
    for (int kc = 0; kc < 2; ++kc)
      qfr[qi][kc] = *(const bf16x8*)&Qg[base + (size_t)(q0 + qi * 16 + l15) * 64 + kc * 32 + lg * 8];

  f32x4 o[4][4] = {};
  float mrow[4], lrow[4];
#pragma unroll
  for (int i = 0; i < 4; ++i) { mrow[i] = -1e30f; lrow[i] = 0.f; }

  bf16x8 kfA[2][2], kfB[2][2];
#pragma unroll
  for (int kr = 0; kr < 2; ++kr)
#pragma unroll
    for (int kc = 0; kc < 2; ++kc)
      kfA[kr][kc] = *(const bf16x8*)&Kg[base + (size_t)(kr * 16 + l15) * 64 + kc * 32 + lg * 8];

#define CHUNK(c, KC, KN, PRE) { \
    const int ck = (c) * 32; \
    f32x4 b4[2][4]; \
    _Pragma("unroll") \
    for (int kr = 0; kr < 2; ++kr) \
      _Pragma("unroll") \
      for (int qi = 0; qi < 4; ++qi) \
        b4[kr][qi] = *(const f32x4*)&bias[(q0 + qi * 16 + l15) * 256 + ck + kr * 16 + lg * 4]; \
    f32x4 s[2][4] = {}; \
    _Pragma("unroll") \
    for (int kr = 0; kr < 2; ++kr) \
      _Pragma("unroll") \
      for (int qi = 0; qi < 4; ++qi) \
        _Pragma("unroll") \
        for (int kc = 0; kc < 2; ++kc) \
          s[kr][qi] = __builtin_amdgcn_mfma_f32_16x16x32_bf16(KC[kr][kc], qfr[qi][kc], s[kr][qi], 0, 0, 0); \
    if (PRE) { \
      _Pragma("unroll") \
      for (int kr = 0; kr < 2; ++kr) \
        _Pragma("unroll") \
        for (int kc = 0; kc < 2; ++kc) \
          KN[kr][kc] = *(const bf16x8*)&Kg[base + (size_t)(ck + 32 + kr * 16 + l15) * 64 + kc * 32 + lg * 8]; \
    } \
    bf16x8 vb[4]; \
    _Pragma("unroll") \
    for (int df = 0; df < 4; ++df) \
      vb[df] = *(const bf16x8*)&VTg[base + (size_t)(df * 16 + l15) * 256 + ck + lg * 8]; \
    float cmax[4]; \
    _Pragma("unroll") \
    for (int qi = 0; qi < 4; ++qi) cmax[qi] = -1e30f; \
    _Pragma("unroll") \
    for (int kr = 0; kr < 2; ++kr) \
      _Pragma("unroll") \
      for (int qi = 0; qi < 4; ++qi) \
        _Pragma("unroll") \
        for (int r = 0; r < 4; ++r) { \
          float v = s[kr][qi][r] * 0.125f + b4[kr][qi][r]; \
          s[kr][qi][r] = v; \
          cmax[qi] = fmaxf(cmax[qi], v); \
        } \
    _Pragma("unroll") \
    for (int qi = 0; qi < 4; ++qi) { \
      cmax[qi] = fmaxf(cmax[qi], __shfl_xor(cmax[qi], 16, 64)); \
      cmax[qi] = fmaxf(cmax[qi], __shfl_xor(cmax[qi], 32, 64)); \
    } \
    float resc[4], csum[4]; \
    _Pragma("unroll") \
    for (int qi = 0; qi < 4; ++qi) { \
      float mn = fmaxf(mrow[qi], cmax[qi]); \
      resc[qi] = __expf(mrow[qi] - mn); \
      mrow[qi] = mn; \
      csum[qi] = 0.f; \
    } \
    _Pragma("unroll") \
    for (int kr = 0; kr < 2; ++kr) \
      _Pragma("unroll") \
      for (int qi = 0; qi < 4; ++qi) \
        _Pragma("unroll") \
        for (int r = 0; r < 4; ++r) { \
          float e = __expf(s[kr][qi][r] - mrow[qi]); \
          s[kr][qi][r] = e; \
          csum[qi] += e; \
        } \
    _Pragma("unroll") \
    for (int qi = 0; qi < 4; ++qi) { \
      csum[qi] += __shfl_xor(csum[qi], 16, 64); \
      csum[qi] += __shfl_xor(csum[qi], 32, 64); \
      lrow[qi] = lrow[qi] * resc[qi] + csum[qi]; \
    } \
    _Pragma("unroll") \
    for (int kr = 0; kr < 2; ++kr) \
      _Pragma("unroll") \
      for (int qi = 0; qi < 4; ++qi) { \
        unsigned long long pk = 0; \
        _Pragma("unroll") \
        for (int r = 0; r < 4; ++r) \
          pk |= (unsigned long long)f2bf(s[kr][qi][r]) << (16 * r); \
        *(unsigned long long*)&P[wave][qi * 16 + l15][kr * 16 + lg * 4] = pk; \
      } \
    asm volatile("s_waitcnt lgkmcnt(0)" ::: "memory"); \
    _Pragma("unroll") \
    for (int qrf = 0; qrf < 4; ++qrf) \
      _Pragma("unroll") \
      for (int r = 0; r < 4; ++r) { \
        float f = __shfl(resc[qrf], lg * 4 + r, 64); \
        _Pragma("unroll") \
        for (int df = 0; df < 4; ++df) o[qrf][df][r] *= f; \
      } \
    bf16x8 pa[4]; \
    _Pragma("unroll") \
    for (int qrf = 0; qrf < 4; ++qrf) \
      pa[qrf] = *(const bf16x8*)&P[wave][qrf * 16 + l15][lg * 8]; \
    _Pragma("unroll") \
    for (int qrf = 0; qrf < 4; ++qrf) \
      _Pragma("unroll") \
      for (int df = 0; df < 4; ++df) \
        o[qrf][df] = __builtin_amdgcn_mfma_f32_16x16x32_bf16(pa[qrf], vb[df], o[qrf][df], 0, 0, 0); \
  }

#pragma unroll 1
  for (int c2 = 0; c2 < 4; ++c2) {
    CHUNK(2 * c2,     kfA, kfB, 1)
    CHUNK(2 * c2 + 1, kfB, kfA, (c2 < 3))
  }
#undef CHUNK

  // normalize and write ctx [B,S,E] bf16
#pragma unroll
  for (int qrf = 0; qrf < 4; ++qrf)
#pragma unroll
    for (int r = 0; r < 4; ++r) {
      float li = __shfl(lrow[qrf], lg * 4 + r, 64);
      float inv = 1.0f / li;
      const int q = q0 + qrf * 16 + lg * 4 + r;
#pragma unroll
      for (int df = 0; df < 4; ++df) {
        const int d = df * 16 + l15;
        ctx[((size_t)(bb * 256 + q) * 16 + hh) * 64 + d] = f2bf(o[qrf][df][r] * inv);
      }
    }
}

// ---------------------------------------------------------------- launch
extern "C" void kernel_launch(void* const* d_in, const int* in_sizes, int n_in,
                              void* d_out, int out_size, void* d_ws, size_t ws_size,
                              hipStream_t stream) {
  const float* x  = (const float*)d_in[0];
  const float* wi = (const float*)d_in[1];
  const float* bi = (const float*)d_in[2];
  const float* wo = (const float*)d_in[3];
  const float* bo = (const float*)d_in[4];
  const float* sb = (const float*)d_in[5];
  float* out = (float*)d_out;

  char* ws = (char*)d_ws;
  // ws layout (bytes): x_bf/ctx 33554432 | w_in 6291456 | w_out 2097152 | Q | K | VT
  unsigned short* xbf  = (unsigned short*)(ws);
  unsigned short* winb = (unsigned short*)(ws + 33554432u);
  unsigned short* wob  = (unsigned short*)(ws + 39845888u);
  unsigned short* Qb   = (unsigned short*)(ws + 41943040u);
  unsigned short* Kb   = (unsigned short*)(ws + 75497472u);
  unsigned short* VTb  = (unsigned short*)(ws + 109051904u);
  unsigned short* ctx  = xbf;   // x_bf dead after QKV GEMM; reuse for ctx

  // 72KB dynamic LDS needs the attribute raised past the 64KB default
  (void)hipFuncSetAttribute(reinterpret_cast<const void*>(gemm4<0>),
                            hipFuncAttributeMaxDynamicSharedMemorySize, 73728);
  (void)hipFuncSetAttribute(reinterpret_cast<const void*>(gemm4<1>),
                            hipFuncAttributeMaxDynamicSharedMemorySize, 73728);

  cvt_kernel<<<16384, 256, 0, stream>>>(x, xbf, 16777216);
  cvt_kernel<<<3072, 256, 0, stream>>>(wi, winb, 3145728);
  cvt_kernel<<<1024, 256, 0, stream>>>(wo, wob, 1048576);

  // QKV: M=16384 N=3072 K=1024
  gemm4<0><<<dim3(64, 24), 256, 73728, stream>>>(xbf, winb, bi, Qb, Kb, VTb, nullptr, nullptr);

  // attention: one block per (b,h)
  attn_kernel<<<1024, 256, 0, stream>>>(Qb, Kb, VTb, sb, ctx);

  // out-proj + residual: M=16384 N=1024 K=1024
  gemm4<1><<<dim3(64, 8), 256, 73728, stream>>>(ctx, wob, bo, nullptr, nullptr, nullptr, x, out);
}

// Round 8
// 280.303 us; speedup vs baseline: 1.1088x; 1.1088x over previous
//
#include <hip/hip_runtime.h>
#include <hip/hip_bf16.h>
#include <stdint.h>

// SpatialMHA: B=64 S=256 E=1024 H=16 D=64
// qkv = x @ Win^T + bin ; attn with additive spatial bias ; out = x + ctx @ Wout^T + bout

typedef __attribute__((ext_vector_type(8))) __bf16 bf16x8;
typedef __attribute__((ext_vector_type(4))) float f32x4;

#define DEVI static __device__ __forceinline__

DEVI unsigned short f2bf(float f) {           // fp32 -> bf16 round-to-nearest-even
  union { float f; unsigned u; } x; x.f = f;
  unsigned r = x.u + 0x7fffu + ((x.u >> 16) & 1u);
  return (unsigned short)(r >> 16);
}

typedef unsigned int __attribute__((address_space(1))) u32_g;
typedef unsigned int __attribute__((address_space(3))) u32_l;

DEVI void g2l16(const unsigned short* g, unsigned short* l) {
  // async global->LDS, 16B per lane; LDS dest = wave-uniform base + lane*16
  __builtin_amdgcn_global_load_lds((const u32_g*)g, (u32_l*)l, 16, 0, 0);
}

// ---------------------------------------------------------------- fp32->bf16
__global__ __launch_bounds__(256) void cvt_kernel(const float* __restrict__ s,
                                                  unsigned short* __restrict__ d, int n) {
  int i = (blockIdx.x * 256 + threadIdx.x) * 4;
  if (i >= n) return;
  float4 v = *(const float4*)(s + i);
  ushort4 o;
  o.x = f2bf(v.x); o.y = f2bf(v.y); o.z = f2bf(v.z); o.w = f2bf(v.w);
  *(ushort4*)(d + i) = o;
}

// ---------------------------------------------------------------- 256x128 GEMM, 4 waves
// (unchanged from R5: 141 us, MfmaUtil 32%, 0 bank conflicts, no spill)
template <int EPI>
__global__ __launch_bounds__(256, 2)
void gemm4(const unsigned short* __restrict__ A,
           const unsigned short* __restrict__ Bw,
           const float* __restrict__ bias,
           unsigned short* __restrict__ Qo,
           unsigned short* __restrict__ Ko,
           unsigned short* __restrict__ VTo,
           const float* __restrict__ Xres,
           float* __restrict__ Out) {
  extern __shared__ unsigned short lds[];   // 3 * 12288 elems (A 8192 + B 4096 each)
  const int lane = threadIdx.x & 63, wid = threadIdx.x >> 6;
  const int l15 = lane & 15, lg = lane >> 4;
  const int wr = wid >> 1, wcn = wid & 1;
  const int am0 = blockIdx.x * 256, bn0 = blockIdx.y * 128;

  const int srow0 = wid * 16 + (lane >> 2);   // 0..63 staging row (+ j*64)
  const int scb0  = (lane & 3) * 16;          // staging linear col-byte

  f32x4 acc[8][4] = {};
  bf16x8 a[8], b[4];

#define SWZ(row) ((((row) >> 1) & 3) << 4)
#define VMC(N) asm volatile("s_waitcnt vmcnt(" #N ")" ::: "memory")

#define STAGE(s) { \
    const int slot_ = (s) % 3; \
    _Pragma("unroll") \
    for (int j = 0; j < 4; ++j) { \
      const int row_ = j * 64 + srow0; \
      const int cs_ = scb0 ^ SWZ(row_); \
      g2l16(A + (size_t)(am0 + row_) * 1024 + (s) * 32 + (cs_ >> 1), \
            &lds[slot_ * 12288 + (j * 64 + wid * 16) * 32]); \
    } \
    _Pragma("unroll") \
    for (int j = 0; j < 2; ++j) { \
      const int row_ = j * 64 + srow0; \
      const int cs_ = scb0 ^ SWZ(row_); \
      g2l16(Bw + (size_t)(bn0 + row_) * 1024 + (s) * 32 + (cs_ >> 1), \
            &lds[slot_ * 12288 + 8192 + (j * 64 + wid * 16) * 32]); \
    } }

#define LOADF(p) { \
    const unsigned short* As_ = &lds[((p) % 3) * 12288]; \
    const unsigned short* Bs_ = As_ + 8192; \
    _Pragma("unroll") \
    for (int mf = 0; mf < 8; ++mf) { \
      const int row_ = wr * 128 + mf * 16 + l15; \
      a[mf] = *(const bf16x8*)((const char*)As_ + row_ * 64 + ((lg * 16) ^ SWZ(row_))); \
    } \
    _Pragma("unroll") \
    for (int nf = 0; nf < 4; ++nf) { \
      const int row_ = wcn * 64 + nf * 16 + l15; \
      b[nf] = *(const bf16x8*)((const char*)Bs_ + row_ * 64 + ((lg * 16) ^ SWZ(row_))); \
    } }

#define MM() { \
    __builtin_amdgcn_s_setprio(1); \
    _Pragma("unroll") \
    for (int mf = 0; mf < 8; ++mf) \
      _Pragma("unroll") \
      for (int nf = 0; nf < 4; ++nf) \
        acc[mf][nf] = __builtin_amdgcn_mfma_f32_16x16x32_bf16(a[mf], b[nf], acc[mf][nf], 0, 0, 0); \
    __builtin_amdgcn_s_setprio(0); }

  STAGE(0) STAGE(1)
  VMC(6);   // slab0 landed (this wave); slab1 in flight

#pragma unroll 1
  for (int p = 0; p < 32; ++p) {
    __builtin_amdgcn_s_barrier();
    if (p < 30) STAGE(p + 2)
    LOADF(p)
    asm volatile("s_waitcnt lgkmcnt(0)" ::: "memory");
    __builtin_amdgcn_sched_barrier(0);
    MM()
    if (p < 29) { VMC(6); } else { VMC(0); }
  }

  // C frag mapping: col = bn0 + wcn*64 + nf*16 + l15 ; row = am0 + wr*128 + mf*16 + lg*4 + r
  if (EPI == 0) {
#pragma unroll
    for (int nf = 0; nf < 4; ++nf) {
      const int col = bn0 + wcn * 64 + nf * 16 + l15;   // 0..3071
      const int which = col >> 10;                      // 0=Q 1=K 2=V (uniform per block)
      const int e = col & 1023;
      const int hh = e >> 6, dd = e & 63;
      const float bv = bias[col];
#pragma unroll
      for (int mf = 0; mf < 8; ++mf) {
        const int row0 = am0 + wr * 128 + mf * 16 + lg * 4;  // multiple of 4
        const int bb = row0 >> 8;
        const int s0 = row0 & 255;
        if (which == 2) {
          unsigned long long pk = 0;
#pragma unroll
          for (int r = 0; r < 4; ++r)
            pk |= (unsigned long long)f2bf(acc[mf][nf][r] + bv) << (16 * r);
          *(unsigned long long*)&VTo[((size_t)(bb * 16 + hh) * 64 + dd) * 256 + s0] = pk;
        } else {
          unsigned short* dst = (which == 0) ? Qo : Ko;
#pragma unroll
          for (int r = 0; r < 4; ++r)
            dst[((size_t)(bb * 16 + hh) * 256 + s0 + r) * 64 + dd] = f2bf(acc[mf][nf][r] + bv);
        }
      }
    }
  } else {
#pragma unroll
    for (int nf = 0; nf < 4; ++nf) {
      const int col = bn0 + wcn * 64 + nf * 16 + l15;
      const float bv = bias[col];
#pragma unroll
      for (int mf = 0; mf < 8; ++mf) {
#pragma unroll
        for (int r = 0; r < 4; ++r) {
          const int row = am0 + wr * 128 + mf * 16 + lg * 4 + r;
          const size_t idx = (size_t)row * 1024 + col;
          Out[idx] = Xres[idx] + acc[mf][nf][r] + bv;
        }
      }
    }
  }
#undef SWZ
#undef VMC
#undef STAGE
#undef LOADF
#undef MM
}

// ---------------------------------------------------------------- fused attention
// One block per (b,h); 4 waves x 64 q rows; 8 key chunks of 32.
// R7 fix vs R6 (which raced): the bulk K-stage handshake was
//   [8x global_load_lds][8x Q global loads] vmcnt(8) barrier
// assuming issue order pins the oldest-8 = the K stages. The compiler may
// reorder the pure Q loads around the staging builtins -> vmcnt(8) can retire
// with K-writes still in flight -> OTHER waves read unlanded LDS rows after the
// barrier (intermittent post-timing divergence). Fix: vmcnt(0)+sched_barrier(0)
// before the barrier (order-independent), Q loads moved after the barrier.
//  (a) K (256x64 bf16, 32KB) bulk-staged to LDS, granule-XOR swizzle
//      (g ^= row&7; uniform 8 lanes/granule = the b128 floor). Source
//      pre-swizzled, linear LDS dest (rule #21).
//  (b) T13 defer-max: skip O-rescale when __all(cmax - mrow <= 8).
// LDS = 32K (K) + 20K (P) = 52KB -> 2 blocks/CU.
__global__ __launch_bounds__(256, 2)
void attn_kernel(const unsigned short* __restrict__ Qg,
                 const unsigned short* __restrict__ Kg,
                 const unsigned short* __restrict__ VTg,
                 const float* __restrict__ bias,
                 unsigned short* __restrict__ ctx) {
  __shared__ unsigned short Ks[256 * 64];   // 32KB swizzled K
  __shared__ unsigned short P[4][64][40];   // per-wave [q][k32], pad 32->40 (20KB)
  const int lane = threadIdx.x & 63, wave = threadIdx.x >> 6;
  const int l15 = lane & 15, lg = lane >> 4;
  const int bh = blockIdx.x;
  const int bb = bh >> 4, hh = bh & 15;
  const size_t base = (size_t)bh * (256 * 64);
  const int q0 = wave * 64;

  // ---- bulk K stage: 2048 granules(16B); issue j covers rows (wave*8+j)*8..+7
#pragma unroll
  for (int j = 0; j < 8; ++j) {
    const int r0 = (wave * 8 + j) * 8;
    const int row = r0 + (lane >> 3);
    const int gsrc = (lane & 7) ^ (row & 7);
    g2l16(&Kg[base + (size_t)row * 64 + gsrc * 8], &Ks[r0 * 64]);
  }
  // Order-independent drain: ALL this wave's vmem done before signaling.
  asm volatile("s_waitcnt vmcnt(0)" ::: "memory");
  __builtin_amdgcn_sched_barrier(0);
  __builtin_amdgcn_s_barrier();                     // all waves' K staged

  // Q fragments (after barrier; compiler inserts waits before first MFMA use)
  bf16x8 qfr[4][2];
#pragma unroll
  for (int qi = 0; qi < 4; ++qi)
#pragma unroll
    for (int kc = 0; kc < 2; ++kc)
      qfr[qi][kc] = *(const bf16x8*)&Qg[base + (size_t)(q0 + qi * 16 + l15) * 64 + kc * 32 + lg * 8];

  f32x4 o[4][4] = {};
  float mrow[4], lrow[4];
#pragma unroll
  for (int i = 0; i < 4; ++i) { mrow[i] = -1e30f; lrow[i] = 0.f; }

#pragma unroll 1
  for (int c = 0; c < 8; ++c) {
    const int ck = c * 32;
    // V + bias issues first (global; longest latency to use)
    bf16x8 vb[4];
#pragma unroll
    for (int df = 0; df < 4; ++df)
      vb[df] = *(const bf16x8*)&VTg[base + (size_t)(df * 16 + l15) * 256 + ck + lg * 8];
    f32x4 b4[2][4];
#pragma unroll
    for (int kr = 0; kr < 2; ++kr)
#pragma unroll
      for (int qi = 0; qi < 4; ++qi)
        b4[kr][qi] = *(const f32x4*)&bias[(q0 + qi * 16 + l15) * 256 + ck + kr * 16 + lg * 4];
    // K fragments from LDS (swizzled granule)
    bf16x8 kf[2][2];
#pragma unroll
    for (int kr = 0; kr < 2; ++kr)
#pragma unroll
      for (int kc = 0; kc < 2; ++kc) {
        const int row = ck + kr * 16 + l15;
        const int g = (kc * 4 + lg) ^ (row & 7);
        kf[kr][kc] = *(const bf16x8*)&Ks[row * 64 + g * 8];
      }
    // S^T chunk [32k x 64q] = mfma(K, Q)
    f32x4 s[2][4] = {};
#pragma unroll
    for (int kr = 0; kr < 2; ++kr)
#pragma unroll
      for (int qi = 0; qi < 4; ++qi)
#pragma unroll
        for (int kc = 0; kc < 2; ++kc)
          s[kr][qi] = __builtin_amdgcn_mfma_f32_16x16x32_bf16(kf[kr][kc], qfr[qi][kc], s[kr][qi], 0, 0, 0);

    // scale + bias; per-q chunk max
    float cmax[4];
#pragma unroll
    for (int qi = 0; qi < 4; ++qi) cmax[qi] = -1e30f;
#pragma unroll
    for (int kr = 0; kr < 2; ++kr)
#pragma unroll
      for (int qi = 0; qi < 4; ++qi)
#pragma unroll
        for (int r = 0; r < 4; ++r) {
          float v = s[kr][qi][r] * 0.125f + b4[kr][qi][r];
          s[kr][qi][r] = v;
          cmax[qi] = fmaxf(cmax[qi], v);
        }
#pragma unroll
    for (int qi = 0; qi < 4; ++qi) {
      cmax[qi] = fmaxf(cmax[qi], __shfl_xor(cmax[qi], 16, 64));
      cmax[qi] = fmaxf(cmax[qi], __shfl_xor(cmax[qi], 32, 64));
    }
    // T13 defer-max: skip rescale when no q-row grew its max by >8
    int defer = 1;
#pragma unroll
    for (int qi = 0; qi < 4; ++qi) defer &= (cmax[qi] - mrow[qi] <= 8.f);
    const int full = !__all(defer);   // wave-uniform
    float resc[4];
#pragma unroll
    for (int qi = 0; qi < 4; ++qi) {
      if (full) {
        float mn = fmaxf(mrow[qi], cmax[qi]);
        resc[qi] = __expf(mrow[qi] - mn);
        mrow[qi] = mn;
      } else resc[qi] = 1.f;
    }
    float csum[4];
#pragma unroll
    for (int qi = 0; qi < 4; ++qi) csum[qi] = 0.f;
#pragma unroll
    for (int kr = 0; kr < 2; ++kr)
#pragma unroll
      for (int qi = 0; qi < 4; ++qi)
#pragma unroll
        for (int r = 0; r < 4; ++r) {
          float e = __expf(s[kr][qi][r] - mrow[qi]);
          s[kr][qi][r] = e;
          csum[qi] += e;
        }
#pragma unroll
    for (int qi = 0; qi < 4; ++qi) {
      csum[qi] += __shfl_xor(csum[qi], 16, 64);
      csum[qi] += __shfl_xor(csum[qi], 32, 64);
      lrow[qi] = lrow[qi] * resc[qi] + csum[qi];
    }
    // P -> LDS transposed to [q][k] (per-wave private), packed b64 writes
#pragma unroll
    for (int kr = 0; kr < 2; ++kr)
#pragma unroll
      for (int qi = 0; qi < 4; ++qi) {
        unsigned long long pk = 0;
#pragma unroll
        for (int r = 0; r < 4; ++r)
          pk |= (unsigned long long)f2bf(s[kr][qi][r]) << (16 * r);
        *(unsigned long long*)&P[wave][qi * 16 + l15][kr * 16 + lg * 4] = pk;
      }
    asm volatile("s_waitcnt lgkmcnt(0)" ::: "memory");
    // O rescale only on the full path (16 bpermutes + 64 mults saved otherwise)
    if (full) {
#pragma unroll
      for (int qrf = 0; qrf < 4; ++qrf)
#pragma unroll
        for (int r = 0; r < 4; ++r) {
          float f = __shfl(resc[qrf], lg * 4 + r, 64);
#pragma unroll
          for (int df = 0; df < 4; ++df) o[qrf][df][r] *= f;
        }
    }
    // PV: A = P[q][k] from LDS, B = V chunk
    bf16x8 pa[4];
#pragma unroll
    for (int qrf = 0; qrf < 4; ++qrf)
      pa[qrf] = *(const bf16x8*)&P[wave][qrf * 16 + l15][lg * 8];
#pragma unroll
    for (int qrf = 0; qrf < 4; ++qrf)
#pragma unroll
      for (int df = 0; df < 4; ++df)
        o[qrf][df] = __builtin_amdgcn_mfma_f32_16x16x32_bf16(pa[qrf], vb[df], o[qrf][df], 0, 0, 0);
  }

  // normalize and write ctx [B,S,E] bf16
#pragma unroll
  for (int qrf = 0; qrf < 4; ++qrf)
#pragma unroll
    for (int r = 0; r < 4; ++r) {
      float li = __shfl(lrow[qrf], lg * 4 + r, 64);
      float inv = 1.0f / li;
      const int q = q0 + qrf * 16 + lg * 4 + r;
#pragma unroll
      for (int df = 0; df < 4; ++df) {
        const int d = df * 16 + l15;
        ctx[((size_t)(bb * 256 + q) * 16 + hh) * 64 + d] = f2bf(o[qrf][df][r] * inv);
      }
    }
}

// ---------------------------------------------------------------- launch
extern "C" void kernel_launch(void* const* d_in, const int* in_sizes, int n_in,
                              void* d_out, int out_size, void* d_ws, size_t ws_size,
                              hipStream_t stream) {
  const float* x  = (const float*)d_in[0];
  const float* wi = (const float*)d_in[1];
  const float* bi = (const float*)d_in[2];
  const float* wo = (const float*)d_in[3];
  const float* bo = (const float*)d_in[4];
  const float* sb = (const float*)d_in[5];
  float* out = (float*)d_out;

  char* ws = (char*)d_ws;
  // ws layout (bytes): x_bf/ctx 33554432 | w_in 6291456 | w_out 2097152 | Q | K | VT
  unsigned short* xbf  = (unsigned short*)(ws);
  unsigned short* winb = (unsigned short*)(ws + 33554432u);
  unsigned short* wob  = (unsigned short*)(ws + 39845888u);
  unsigned short* Qb   = (unsigned short*)(ws + 41943040u);
  unsigned short* Kb   = (unsigned short*)(ws + 75497472u);
  unsigned short* VTb  = (unsigned short*)(ws + 109051904u);
  unsigned short* ctx  = xbf;   // x_bf dead after QKV GEMM; reuse for ctx

  // 72KB dynamic LDS needs the attribute raised past the 64KB default
  (void)hipFuncSetAttribute(reinterpret_cast<const void*>(gemm4<0>),
                            hipFuncAttributeMaxDynamicSharedMemorySize, 73728);
  (void)hipFuncSetAttribute(reinterpret_cast<const void*>(gemm4<1>),
                            hipFuncAttributeMaxDynamicSharedMemorySize, 73728);

  cvt_kernel<<<16384, 256, 0, stream>>>(x, xbf, 16777216);
  cvt_kernel<<<3072, 256, 0, stream>>>(wi, winb, 3145728);
  cvt_kernel<<<1024, 256, 0, stream>>>(wo, wob, 1048576);

  // QKV: M=16384 N=3072 K=1024
  gemm4<0><<<dim3(64, 24), 256, 73728, stream>>>(xbf, winb, bi, Qb, Kb, VTb, nullptr, nullptr);

  // attention: one block per (b,h)
  attn_kernel<<<1024, 256, 0, stream>>>(Qb, Kb, VTb, sb, ctx);

  // out-proj + residual: M=16384 N=1024 K=1024
  gemm4<1><<<dim3(64, 8), 256, 73728, stream>>>(ctx, wob, bo, nullptr, nullptr, nullptr, x, out);
}